// Round 3
// baseline (3158.005 us; speedup 1.0000x reference)
//
#include <hip/hip_runtime.h>
#include <cstdint>

#define SEQ 2048
#define BATCH 2
#define NTOK 4096      // B*S
#define HID 2048
#define NH 32
#define NKV 4
#define HD 128
#define QKV_O 5120     // (32+8)*128

typedef __attribute__((ext_vector_type(8))) short short8;
typedef __attribute__((ext_vector_type(4))) float f32x4;
typedef __attribute__((ext_vector_type(4))) unsigned short u16x4;
typedef unsigned short ushort_t;

__device__ __forceinline__ float bf2f(unsigned short u) {
  union { unsigned int i; float f; } v; v.i = ((unsigned int)u) << 16; return v.f;
}
__device__ __forceinline__ unsigned short f2bf(float f) {
  union { float f; unsigned int i; } v; v.f = f;
  unsigned int r = v.i + 0x7FFFu + ((v.i >> 16) & 1u);
  return (unsigned short)(r >> 16);
}

// ---------------------------------------------------------------------------
// fp32 -> bf16 (round-to-nearest-even), vectorized. n must be divisible by 4.
// ---------------------------------------------------------------------------
__global__ __launch_bounds__(256) void convert_to_bf16(const float* __restrict__ src,
                                                       unsigned short* __restrict__ dst,
                                                       int n4) {
  int i = blockIdx.x * blockDim.x + threadIdx.x;
  int stride = gridDim.x * blockDim.x;
  for (; i < n4; i += stride) {
    f32x4 v = *(const f32x4*)(src + 4 * (size_t)i);
    u16x4 o;
    o.x = f2bf(v.x); o.y = f2bf(v.y); o.z = f2bf(v.z); o.w = f2bf(v.w);
    *(u16x4*)(dst + 4 * (size_t)i) = o;
  }
}

// ---------------------------------------------------------------------------
// C[M,N] = A[M,K] * B[N,K]^T, bf16 in, fp32 accum, bf16 OR fp32 out (OUT_F32).
// 128x128 tile, BK=32, 4 waves (2x2 of 64x64), mfma_f32_16x16x32_bf16.
// Fragment layouts (m89/m91-verified): A/B: m|n=lane&15, k=(lane>>4)*8+j.
// C/D: col=lane&15, row=(lane>>4)*4+reg.
// ---------------------------------------------------------------------------
template <bool OUT_F32>
__global__ __launch_bounds__(256) void gemm_bt_bf16(
    const unsigned short* __restrict__ A, const unsigned short* __restrict__ B,
    void* __restrict__ Cv, int lda, int ldb, int ldc, int K) {
  __shared__ alignas(16) unsigned short As[128 * 40];  // pad 32 -> 40
  __shared__ alignas(16) unsigned short Bs[128 * 40];

  const int t    = threadIdx.x;
  const int lane = t & 63;
  const int w    = t >> 6;
  const int wm   = (w >> 1) * 64;
  const int wn   = (w & 1) * 64;
  const size_t m0 = (size_t)blockIdx.y * 128;
  const size_t n0 = (size_t)blockIdx.x * 128;

  f32x4 acc[4][4] = {};

  const int r0 = t >> 2;        // 0..63
  const int c0 = (t & 3) * 8;   // 0,8,16,24
  const int fr = lane & 15;
  const int kb = (lane >> 4) * 8;

  for (int k0 = 0; k0 < K; k0 += 32) {
    *(uint4*)&As[r0 * 40 + c0]        = *(const uint4*)&A[(m0 + r0) * lda + k0 + c0];
    *(uint4*)&As[(r0 + 64) * 40 + c0] = *(const uint4*)&A[(m0 + r0 + 64) * lda + k0 + c0];
    *(uint4*)&Bs[r0 * 40 + c0]        = *(const uint4*)&B[(n0 + r0) * ldb + k0 + c0];
    *(uint4*)&Bs[(r0 + 64) * 40 + c0] = *(const uint4*)&B[(n0 + r0 + 64) * ldb + k0 + c0];
    __syncthreads();
    short8 af[4], bf[4];
#pragma unroll
    for (int mt = 0; mt < 4; mt++) af[mt] = *(const short8*)&As[(wm + mt * 16 + fr) * 40 + kb];
#pragma unroll
    for (int nt = 0; nt < 4; nt++) bf[nt] = *(const short8*)&Bs[(wn + nt * 16 + fr) * 40 + kb];
#pragma unroll
    for (int mt = 0; mt < 4; mt++)
#pragma unroll
      for (int nt = 0; nt < 4; nt++)
        acc[mt][nt] = __builtin_amdgcn_mfma_f32_16x16x32_bf16(af[mt], bf[nt], acc[mt][nt], 0, 0, 0);
    __syncthreads();
  }

  const int r4 = (lane >> 4) * 4;
  const int cc = lane & 15;
#pragma unroll
  for (int mt = 0; mt < 4; mt++)
#pragma unroll
    for (int nt = 0; nt < 4; nt++) {
      size_t row = m0 + wm + mt * 16 + r4;
      size_t col = n0 + wn + nt * 16 + cc;
#pragma unroll
      for (int r = 0; r < 4; r++) {
        if (OUT_F32) ((float*)Cv)[(row + r) * ldc + col] = acc[mt][nt][r];
        else ((unsigned short*)Cv)[(row + r) * ldc + col] = f2bf(acc[mt][nt][r]);
      }
    }
}

// ---------------------------------------------------------------------------
// RMSNorm + RoPE, IN PLACE on qkv. One wave per (token, q-or-k head).
// Lane i owns dims i and i+64 (the rotate-half pair). v heads untouched.
// ---------------------------------------------------------------------------
__global__ __launch_bounds__(64) void normrope(
    unsigned short* __restrict__ qkv, const int* __restrict__ pos,
    const unsigned short* __restrict__ qw, const unsigned short* __restrict__ kw) {
  const int h    = blockIdx.x;                       // 0..35 (32 q + 4 k)
  const int tok  = blockIdx.z * SEQ + blockIdx.y;
  const int lane = threadIdx.x;                      // 0..63

  const unsigned short* w = (h < NH) ? qw : kw;
  const size_t src = (size_t)tok * QKV_O + (size_t)h * HD;  // q then k slots are contiguous

  float x1 = bf2f(qkv[src + lane]);
  float x2 = bf2f(qkv[src + lane + 64]);
  float ss = x1 * x1 + x2 * x2;
#pragma unroll
  for (int off = 32; off; off >>= 1) ss += __shfl_xor(ss, off);
  float r = rsqrtf(ss * (1.0f / 128.0f) + 1e-6f);
  float n1 = x1 * r * bf2f(w[lane]);
  float n2 = x2 * r * bf2f(w[lane + 64]);

  float p = (float)pos[tok];
  float inv_freq = expf((float)lane * (-13.815510557964274f / 64.0f));  // 1e6^(-lane/64)
  float ang = p * inv_freq;
  float c = cosf(ang), s = sinf(ang);
  qkv[src + lane]      = f2bf(n1 * c - n2 * s);
  qkv[src + lane + 64] = f2bf(n2 * c + n1 * s);
}

// ---------------------------------------------------------------------------
// Causal GQA flash attention, scalar-VALU version, reading strided q/k/v from
// the qkv buffer and writing attn IN PLACE into the q region (each cell is
// read only by the block that writes it; k/v regions are never written).
// Block: 256 threads, 32 q-rows, K/V tiles of 32. thread t: row i=t>>3, jg=t&7.
// ---------------------------------------------------------------------------
__global__ __launch_bounds__(256) void flash(unsigned short* __restrict__ qkv) {
  __shared__ alignas(16) float q_s[32][132];
  __shared__ alignas(16) float k_s[32][132];
  __shared__ alignas(16) float v_s[32][132];
  __shared__ float p_s[32][33];
  __shared__ float m_s[32], l_s[32];

  const int qt = blockIdx.x, h = blockIdx.y, b = blockIdx.z;
  const int t = threadIdx.x;
  const int kvh = h >> 3;      // GQA: 32 q-heads -> 4 kv-heads
  const int q0 = qt * 32;
  const int i  = t >> 3;
  const int jg = t & 7;
  const int qi = q0 + i;
  const float scale = 0.08838834764831845f;  // 128^-0.5

  for (int idx = t; idx < 32 * 128; idx += 256) {
    int r = idx >> 7, d = idx & 127;
    q_s[r][d] = bf2f(qkv[(size_t)(b * SEQ + q0 + r) * QKV_O + h * HD + d]);
  }
  if (t < 32) { m_s[t] = -1e30f; l_s[t] = 0.0f; }

  f32x4 o[4] = {};

  for (int kt = 0; kt <= qt; kt++) {
    __syncthreads();
    for (int idx = t; idx < 32 * 128; idx += 256) {
      int r = idx >> 7, d = idx & 127;
      size_t row = (size_t)(b * SEQ + kt * 32 + r) * QKV_O;
      k_s[r][d] = bf2f(qkv[row + NH * HD + kvh * HD + d]);
      v_s[r][d] = bf2f(qkv[row + (NH + NKV) * HD + kvh * HD + d]);
    }
    __syncthreads();

    float s0 = 0, s1 = 0, s2 = 0, s3 = 0;
    for (int d4 = 0; d4 < 128; d4 += 4) {
      f32x4 q4 = *(const f32x4*)&q_s[i][d4];
      f32x4 k0v = *(const f32x4*)&k_s[jg][d4];
      f32x4 k1v = *(const f32x4*)&k_s[jg + 8][d4];
      f32x4 k2v = *(const f32x4*)&k_s[jg + 16][d4];
      f32x4 k3v = *(const f32x4*)&k_s[jg + 24][d4];
#pragma unroll
      for (int e = 0; e < 4; e++) {
        s0 += q4[e] * k0v[e];
        s1 += q4[e] * k1v[e];
        s2 += q4[e] * k2v[e];
        s3 += q4[e] * k3v[e];
      }
    }
    float sc[4] = {s0 * scale, s1 * scale, s2 * scale, s3 * scale};
#pragma unroll
    for (int jj = 0; jj < 4; jj++)
      if (kt * 32 + jg + 8 * jj > qi) sc[jj] = -1e30f;

    float mt_ = fmaxf(fmaxf(sc[0], sc[1]), fmaxf(sc[2], sc[3]));
#pragma unroll
    for (int off = 1; off < 8; off <<= 1) mt_ = fmaxf(mt_, __shfl_xor(mt_, off));
    float m_old = m_s[i];
    float m_new = fmaxf(m_old, mt_);
    float alpha = __expf(m_old - m_new);
    float p[4], ps = 0;
#pragma unroll
    for (int jj = 0; jj < 4; jj++) { p[jj] = __expf(sc[jj] - m_new); ps += p[jj]; }
#pragma unroll
    for (int off = 1; off < 8; off <<= 1) ps += __shfl_xor(ps, off);
    float l_new = l_s[i] * alpha + ps;
#pragma unroll
    for (int jj = 0; jj < 4; jj++) p_s[i][jg + 8 * jj] = p[jj];
    __syncthreads();
    if (jg == 0) { m_s[i] = m_new; l_s[i] = l_new; }

#pragma unroll
    for (int g = 0; g < 4; g++) o[g] = o[g] * alpha;
    for (int j = 0; j < 32; j++) {
      float pj = p_s[i][j];
#pragma unroll
      for (int g = 0; g < 4; g++) {
        f32x4 vv = *(const f32x4*)&v_s[j][jg * 4 + 32 * g];
        o[g] += pj * vv;
      }
    }
  }

  __syncthreads();
  float inv_l = 1.0f / l_s[i];
#pragma unroll
  for (int g = 0; g < 4; g++)
#pragma unroll
    for (int e = 0; e < 4; e++)
      k_s[i][jg * 4 + 32 * g + e] = o[g][e] * inv_l;
  __syncthreads();
  for (int idx = t; idx < 32 * 128; idx += 256) {
    int r = idx >> 7, d = idx & 127;
    qkv[(size_t)(b * SEQ + q0 + r) * QKV_O + h * HD + d] = f2bf(k_s[r][d]);
  }
}

// ---------------------------------------------------------------------------
extern "C" void kernel_launch(void* const* d_in, const int* in_sizes, int n_in,
                              void* d_out, int out_size, void* d_ws, size_t ws_size,
                              hipStream_t stream) {
  const float* hidden_f = (const float*)d_in[0];
  const int* positions  = (const int*)d_in[1];
  const float* wqkv_f   = (const float*)d_in[2];
  const float* wo_f     = (const float*)d_in[3];
  const float* qn_f     = (const float*)d_in[4];
  const float* kn_f     = (const float*)d_in[5];
  float* out            = (float*)d_out;  // reference output dtype is float32

  char* ws = (char*)d_ws;
  // Workspace layout (bytes), 256-aligned:
  unsigned short* hidden_c = (unsigned short*)ws;                    // 4096*2048*2  = 16,777,216
  unsigned short* wqkv_c   = (unsigned short*)(ws + 16777216);       // 5120*2048*2  = 20,971,520
  unsigned short* wo_c     = (unsigned short*)(ws + 37748736);       // 2048*4096*2  = 16,777,216
  unsigned short* qn_c     = (unsigned short*)(ws + 54525952);       // 256 B
  unsigned short* kn_c     = (unsigned short*)(ws + 54526208);       // 256 B
  unsigned short* qkv      = (unsigned short*)(ws + 54526464);       // 4096*5120*2  = 41,943,040
  // total ≈ 96,469,504 B ≈ 92 MiB

  convert_to_bf16<<<1024, 256, 0, stream>>>(hidden_f, hidden_c, NTOK * HID / 4);
  convert_to_bf16<<<1024, 256, 0, stream>>>(wqkv_f, wqkv_c, QKV_O * HID / 4);
  convert_to_bf16<<<1024, 256, 0, stream>>>(wo_f, wo_c, HID * NH * HD / 4);
  convert_to_bf16<<<1, 32, 0, stream>>>(qn_f, qn_c, HD / 4);
  convert_to_bf16<<<1, 32, 0, stream>>>(kn_f, kn_c, HD / 4);

  // K1: qkv = hidden @ w_qkv^T   (4096 x 5120 x 2048), bf16 out
  gemm_bt_bf16<false><<<dim3(QKV_O / 128, NTOK / 128), 256, 0, stream>>>(
      hidden_c, wqkv_c, qkv, HID, HID, QKV_O, HID);
  // K2: rmsnorm + rope, in place on q & k head slots
  normrope<<<dim3(NH + NKV, SEQ, BATCH), 64, 0, stream>>>(qkv, positions, qn_c, kn_c);
  // K3: causal GQA attention, attn written in place into q region of qkv
  flash<<<dim3(SEQ / 32, NH, BATCH), 256, 0, stream>>>(qkv);
  // K4: out = attn @ w_o^T   (4096 x 2048 x 4096), fp32 out
  gemm_bt_bf16<true><<<dim3(HID / 128, NTOK / 128), 256, 0, stream>>>(
      qkv, wo_c, out, QKV_O, NH * HD, HID, NH * HD);
}

// Round 4
// 762.693 us; speedup vs baseline: 4.1406x; 4.1406x over previous
//
#include <hip/hip_runtime.h>
#include <cstdint>

#define SEQ 2048
#define BATCH 2
#define NTOK 4096      // B*S
#define HID 2048
#define NH 32
#define NKV 4
#define HD 128
#define QKV_O 5120     // (32+8)*128

typedef __attribute__((ext_vector_type(8))) short short8;
typedef __attribute__((ext_vector_type(8))) unsigned short u16x8;
typedef __attribute__((ext_vector_type(4))) unsigned short u16x4;
typedef __attribute__((ext_vector_type(4))) float f32x4;

__device__ __forceinline__ float bf2f(unsigned short u) {
  union { unsigned int i; float f; } v; v.i = ((unsigned int)u) << 16; return v.f;
}
__device__ __forceinline__ unsigned short f2bf(float f) {
  union { float f; unsigned int i; } v; v.f = f;
  unsigned int r = v.i + 0x7FFFu + ((v.i >> 16) & 1u);
  return (unsigned short)(r >> 16);
}

// ---------------------------------------------------------------------------
// fp32 -> bf16 (round-to-nearest-even), vectorized. n4 = n/4.
// ---------------------------------------------------------------------------
__global__ __launch_bounds__(256) void convert_to_bf16(const float* __restrict__ src,
                                                       unsigned short* __restrict__ dst,
                                                       int n4) {
  int i = blockIdx.x * blockDim.x + threadIdx.x;
  int stride = gridDim.x * blockDim.x;
  for (; i < n4; i += stride) {
    f32x4 v = *(const f32x4*)(src + 4 * (size_t)i);
    u16x4 o;
    o.x = f2bf(v.x); o.y = f2bf(v.y); o.z = f2bf(v.z); o.w = f2bf(v.w);
    *(u16x4*)(dst + 4 * (size_t)i) = o;
  }
}

// ---------------------------------------------------------------------------
// C[M,N] = A[M,K] * B[N,K]^T, bf16 in, fp32 accum, bf16 OR fp32 out (OUT_F32).
// 128x128 tile, BK=32, 4 waves (2x2 of 64x64), mfma_f32_16x16x32_bf16.
// ---------------------------------------------------------------------------
template <bool OUT_F32>
__global__ __launch_bounds__(256) void gemm_bt_bf16(
    const unsigned short* __restrict__ A, const unsigned short* __restrict__ B,
    void* __restrict__ Cv, int lda, int ldb, int ldc, int K) {
  __shared__ alignas(16) unsigned short As[128 * 40];
  __shared__ alignas(16) unsigned short Bs[128 * 40];

  const int t    = threadIdx.x;
  const int lane = t & 63;
  const int w    = t >> 6;
  const int wm   = (w >> 1) * 64;
  const int wn   = (w & 1) * 64;
  const size_t m0 = (size_t)blockIdx.y * 128;
  const size_t n0 = (size_t)blockIdx.x * 128;

  f32x4 acc[4][4] = {};

  const int r0 = t >> 2;
  const int c0 = (t & 3) * 8;
  const int fr = lane & 15;
  const int kb = (lane >> 4) * 8;

  for (int k0 = 0; k0 < K; k0 += 32) {
    *(uint4*)&As[r0 * 40 + c0]        = *(const uint4*)&A[(m0 + r0) * lda + k0 + c0];
    *(uint4*)&As[(r0 + 64) * 40 + c0] = *(const uint4*)&A[(m0 + r0 + 64) * lda + k0 + c0];
    *(uint4*)&Bs[r0 * 40 + c0]        = *(const uint4*)&B[(n0 + r0) * ldb + k0 + c0];
    *(uint4*)&Bs[(r0 + 64) * 40 + c0] = *(const uint4*)&B[(n0 + r0 + 64) * ldb + k0 + c0];
    __syncthreads();
    short8 af[4], bf[4];
#pragma unroll
    for (int mt = 0; mt < 4; mt++) af[mt] = *(const short8*)&As[(wm + mt * 16 + fr) * 40 + kb];
#pragma unroll
    for (int nt = 0; nt < 4; nt++) bf[nt] = *(const short8*)&Bs[(wn + nt * 16 + fr) * 40 + kb];
#pragma unroll
    for (int mt = 0; mt < 4; mt++)
#pragma unroll
      for (int nt = 0; nt < 4; nt++)
        acc[mt][nt] = __builtin_amdgcn_mfma_f32_16x16x32_bf16(af[mt], bf[nt], acc[mt][nt], 0, 0, 0);
    __syncthreads();
  }

  const int r4 = (lane >> 4) * 4;
  const int cc = lane & 15;
#pragma unroll
  for (int mt = 0; mt < 4; mt++)
#pragma unroll
    for (int nt = 0; nt < 4; nt++) {
      size_t row = m0 + wm + mt * 16 + r4;
      size_t col = n0 + wn + nt * 16 + cc;
#pragma unroll
      for (int r = 0; r < 4; r++) {
        if (OUT_F32) ((float*)Cv)[(row + r) * ldc + col] = acc[mt][nt][r];
        else ((unsigned short*)Cv)[(row + r) * ldc + col] = f2bf(acc[mt][nt][r]);
      }
    }
}

// ---------------------------------------------------------------------------
// RMSNorm + RoPE, IN PLACE on qkv. One wave per (token, q-or-k head).
// ---------------------------------------------------------------------------
__global__ __launch_bounds__(64) void normrope(
    unsigned short* __restrict__ qkv, const int* __restrict__ pos,
    const unsigned short* __restrict__ qw, const unsigned short* __restrict__ kw) {
  const int h    = blockIdx.x;                       // 0..35 (32 q + 4 k)
  const int tok  = blockIdx.z * SEQ + blockIdx.y;
  const int lane = threadIdx.x;

  const unsigned short* w = (h < NH) ? qw : kw;
  const size_t src = (size_t)tok * QKV_O + (size_t)h * HD;

  float x1 = bf2f(qkv[src + lane]);
  float x2 = bf2f(qkv[src + lane + 64]);
  float ss = x1 * x1 + x2 * x2;
#pragma unroll
  for (int off = 32; off; off >>= 1) ss += __shfl_xor(ss, off);
  float r = rsqrtf(ss * (1.0f / 128.0f) + 1e-6f);
  float n1 = x1 * r * bf2f(w[lane]);
  float n2 = x2 * r * bf2f(w[lane + 64]);

  float p = (float)pos[tok];
  float inv_freq = expf((float)lane * (-13.815510557964274f / 64.0f));  // 1e6^(-lane/64)
  float ang = p * inv_freq;
  float c = cosf(ang), s = sinf(ang);
  qkv[src + lane]      = f2bf(n1 * c - n2 * s);
  qkv[src + lane + 64] = f2bf(n2 * c + n1 * s);
}

// ---------------------------------------------------------------------------
// MFMA causal GQA flash attention.
// Block: 256 thr (4 waves), q-tile = 64 rows (wave w: rows q0+16w..+15), KV
// tiles of 64. Scores computed TRANSPOSED: ScT[kv][q] = K(64x128) @ Q^T via
// mfma_16x16x32 (A=K rows, B=Q rows, both contiguous in d). C-layout:
// row=kv=(lane>>4)*4+reg, col=q=lane&15 -> per-q softmax = in-lane reduce over
// 16 regs + shfl_xor(16,32). P round-trips LDS (bf16, per-wave region) into
// A-frag layout; PV uses LDS-transposed Vt[d][kv] as B-frags.
// O accum C-layout: row=q, col=d. attn written in place into q region of qkv.
// ---------------------------------------------------------------------------
__global__ __launch_bounds__(256) void flash_mfma(unsigned short* __restrict__ qkv) {
  __shared__ alignas(16) unsigned short Qs[64][136];   // pad 128->136 (2-way banks)
  __shared__ alignas(16) unsigned short Ks[64][136];
  __shared__ alignas(16) unsigned short Vt[128][72];   // pad 64->72
  __shared__ alignas(16) unsigned short Ps[4][16][72]; // per-wave P
  __shared__ alignas(16) float bcast[4][16];           // per-wave col->row bcast

  const int qt = (int)gridDim.x - 1 - (int)blockIdx.x; // heavy blocks first
  const int h = blockIdx.y, b = blockIdx.z;
  const int t = threadIdx.x;
  const int lane = t & 63, w = t >> 6;
  const int c = lane & 15, g = lane >> 4;
  const int q0 = qt * 64;
  const int kvh = h >> 3;                              // GQA 32->4
  const int koff = NH * HD + kvh * HD;
  const int voff = (NH + NKV) * HD + kvh * HD;
  const float scale = 0.08838834764831845f;            // 128^-0.5

  // stage Q (64 x 128), coalesced uint4
  {
    const int row = t >> 2, cb = (t & 3) * 8;
    const size_t gb = (size_t)(b * SEQ + q0 + row) * QKV_O + h * HD;
#pragma unroll
    for (int r = 0; r < 4; r++)
      *(uint4*)&Qs[row][cb + 32 * r] = *(const uint4*)&qkv[gb + cb + 32 * r];
  }
  __syncthreads();

  // preload Q B-frags (4 k-steps of 32 over d)
  short8 qf[4];
#pragma unroll
  for (int ks = 0; ks < 4; ks++)
    qf[ks] = *(const short8*)&Qs[w * 16 + c][ks * 32 + g * 8];

  f32x4 O[8] = {};                // 8 d-tiles x 4 row-regs
  float m_i = -1e30f, l_i = 0.0f; // per-q state (q = col c), replicated x4 groups

  const int nkt = qt + 1;
  for (int kt = 0; kt < nkt; kt++) {
    const int k0 = kt * 64;
    __syncthreads();
    // stage K rows (coalesced uint4)
    {
      const int row = t >> 2, cb = (t & 3) * 8;
      const size_t gb = (size_t)(b * SEQ + k0 + row) * QKV_O + koff;
#pragma unroll
      for (int r = 0; r < 4; r++)
        *(uint4*)&Ks[row][cb + 32 * r] = *(const uint4*)&qkv[gb + cb + 32 * r];
    }
    // stage V transposed: Vt[d][kv]; coalesced scalar loads (lane-per-d),
    // vectorized b128 LDS writes (bank-balanced)
    {
      const int d = t & 127, kh = t >> 7;
#pragma unroll
      for (int r = 0; r < 4; r++) {
        const int kv0 = r * 16 + kh * 8;
        u16x8 vv;
#pragma unroll
        for (int i = 0; i < 8; i++)
          vv[i] = qkv[(size_t)(b * SEQ + k0 + kv0 + i) * QKV_O + voff + d];
        *(u16x8*)&Vt[d][kv0] = vv;
      }
    }
    __syncthreads();

    // ScT[kv 64][q 16] per wave: 4 mt x 4 ks MFMAs
    f32x4 sc[4];
#pragma unroll
    for (int mt = 0; mt < 4; mt++) sc[mt] = (f32x4){0.f, 0.f, 0.f, 0.f};
#pragma unroll
    for (int ks = 0; ks < 4; ks++) {
#pragma unroll
      for (int mt = 0; mt < 4; mt++) {
        short8 kf = *(const short8*)&Ks[mt * 16 + c][ks * 32 + g * 8];
        sc[mt] = __builtin_amdgcn_mfma_f32_16x16x32_bf16(kf, qf[ks], sc[mt], 0, 0, 0);
      }
    }

    // scale + causal mask (wave-uniform branch)
    const int qrow = q0 + w * 16 + c;
    const bool need_mask = (k0 + 63 > q0 + w * 16);
    float scv[16];
#pragma unroll
    for (int mt = 0; mt < 4; mt++)
#pragma unroll
      for (int r = 0; r < 4; r++) {
        float s = sc[mt][r] * scale;
        if (need_mask && (k0 + mt * 16 + g * 4 + r > qrow)) s = -1e30f;
        scv[mt * 4 + r] = s;
      }

    // per-q (column) online softmax
    float mx = scv[0];
#pragma unroll
    for (int i = 1; i < 16; i++) mx = fmaxf(mx, scv[i]);
    mx = fmaxf(mx, __shfl_xor(mx, 16));
    mx = fmaxf(mx, __shfl_xor(mx, 32));
    float m_new = fmaxf(m_i, mx);
    float alpha = __expf(m_i - m_new);
    float psum = 0.0f;
    unsigned short pb[16];
#pragma unroll
    for (int i = 0; i < 16; i++) {
      float p = __expf(scv[i] - m_new);
      psum += p;
      pb[i] = f2bf(p);
    }
    psum += __shfl_xor(psum, 16);
    psum += __shfl_xor(psum, 32);
    l_i = l_i * alpha + psum;
    m_i = m_new;

    // write P[q][kv] bf16 into per-wave region (4 x ds_write_b64)
#pragma unroll
    for (int mt = 0; mt < 4; mt++) {
      u16x4 p4 = {pb[mt * 4 + 0], pb[mt * 4 + 1], pb[mt * 4 + 2], pb[mt * 4 + 3]};
      *(u16x4*)&Ps[w][c][mt * 16 + g * 4] = p4;
    }
    // broadcast alpha from col-space (q=c) to row-space (q=g*4+r)
    if (g == 0) bcast[w][c] = alpha;
    f32x4 a4 = *(const f32x4*)&bcast[w][g * 4];
#pragma unroll
    for (int nt = 0; nt < 8; nt++)
#pragma unroll
      for (int r = 0; r < 4; r++) O[nt][r] *= a4[r];

    // PV: O[q][d] += P(16x64) @ Vt-frags; 2 ks x 8 nt MFMAs
#pragma unroll
    for (int ks = 0; ks < 2; ks++) {
      short8 pf = *(const short8*)&Ps[w][c][ks * 32 + g * 8];
#pragma unroll
      for (int nt = 0; nt < 8; nt++) {
        short8 vf = *(const short8*)&Vt[nt * 16 + c][ks * 32 + g * 8];
        O[nt] = __builtin_amdgcn_mfma_f32_16x16x32_bf16(pf, vf, O[nt], 0, 0, 0);
      }
    }
  }

  // epilogue: O /= l (l bcast col->row), write bf16 in place (q region)
  if (g == 0) bcast[w][c] = l_i;
  f32x4 l4 = *(const f32x4*)&bcast[w][g * 4];
  f32x4 li;
#pragma unroll
  for (int r = 0; r < 4; r++) li[r] = 1.0f / l4[r];
#pragma unroll
  for (int nt = 0; nt < 8; nt++)
#pragma unroll
    for (int r = 0; r < 4; r++) {
      size_t addr = (size_t)(b * SEQ + q0 + w * 16 + g * 4 + r) * QKV_O + h * HD + nt * 16 + c;
      qkv[addr] = f2bf(O[nt][r] * li[r]);
    }
}

// ---------------------------------------------------------------------------
extern "C" void kernel_launch(void* const* d_in, const int* in_sizes, int n_in,
                              void* d_out, int out_size, void* d_ws, size_t ws_size,
                              hipStream_t stream) {
  const float* hidden_f = (const float*)d_in[0];
  const int* positions  = (const int*)d_in[1];
  const float* wqkv_f   = (const float*)d_in[2];
  const float* wo_f     = (const float*)d_in[3];
  const float* qn_f     = (const float*)d_in[4];
  const float* kn_f     = (const float*)d_in[5];
  float* out            = (float*)d_out;  // reference output dtype is float32

  char* ws = (char*)d_ws;
  unsigned short* hidden_c = (unsigned short*)ws;                    // 16,777,216
  unsigned short* wqkv_c   = (unsigned short*)(ws + 16777216);       // 20,971,520
  unsigned short* wo_c     = (unsigned short*)(ws + 37748736);       // 16,777,216
  unsigned short* qn_c     = (unsigned short*)(ws + 54525952);       // 256
  unsigned short* kn_c     = (unsigned short*)(ws + 54526208);       // 256
  unsigned short* qkv      = (unsigned short*)(ws + 54526464);       // 41,943,040

  convert_to_bf16<<<1024, 256, 0, stream>>>(hidden_f, hidden_c, NTOK * HID / 4);
  convert_to_bf16<<<1024, 256, 0, stream>>>(wqkv_f, wqkv_c, QKV_O * HID / 4);
  convert_to_bf16<<<1024, 256, 0, stream>>>(wo_f, wo_c, HID * NH * HD / 4);
  convert_to_bf16<<<1, 32, 0, stream>>>(qn_f, qn_c, HD / 4);
  convert_to_bf16<<<1, 32, 0, stream>>>(kn_f, kn_c, HD / 4);

  // K1: qkv = hidden @ w_qkv^T   (4096 x 5120 x 2048), bf16 out
  gemm_bt_bf16<false><<<dim3(QKV_O / 128, NTOK / 128), 256, 0, stream>>>(
      hidden_c, wqkv_c, qkv, HID, HID, QKV_O, HID);
  // K2: rmsnorm + rope, in place on q & k head slots
  normrope<<<dim3(NH + NKV, SEQ, BATCH), 64, 0, stream>>>(qkv, positions, qn_c, kn_c);
  // K3: MFMA causal GQA attention, attn in place into q region of qkv
  flash_mfma<<<dim3(SEQ / 64, NH, BATCH), 256, 0, stream>>>(qkv);
  // K4: out = attn @ w_o^T   (4096 x 2048 x 4096), fp32 out
  gemm_bt_bf16<true><<<dim3(HID / 128, NTOK / 128), 256, 0, stream>>>(
      qkv, wo_c, out, QKV_O, NH * HD, HID, NH * HD);
}

// Round 5
// 657.539 us; speedup vs baseline: 4.8028x; 1.1599x over previous
//
#include <hip/hip_runtime.h>
#include <cstdint>

#define SEQ 2048
#define BATCH 2
#define NTOK 4096      // B*S
#define HID 2048
#define NH 32
#define NKV 4
#define HD 128
#define QKV_O 5120     // (32+8)*128

typedef __attribute__((ext_vector_type(8))) short short8;
typedef __attribute__((ext_vector_type(8))) unsigned short u16x8;
typedef __attribute__((ext_vector_type(4))) unsigned short u16x4;
typedef __attribute__((ext_vector_type(4))) float f32x4;

__device__ __forceinline__ float bf2f(unsigned short u) {
  union { unsigned int i; float f; } v; v.i = ((unsigned int)u) << 16; return v.f;
}
__device__ __forceinline__ unsigned short f2bf(float f) {
  union { float f; unsigned int i; } v; v.f = f;
  unsigned int r = v.i + 0x7FFFu + ((v.i >> 16) & 1u);
  return (unsigned short)(r >> 16);
}

// async global->LDS, 16 B per lane. LDS dest is wave-uniform base + lane*16.
__device__ __forceinline__ void load_lds16(const void* g, void* l) {
  __builtin_amdgcn_global_load_lds((const __attribute__((address_space(1))) unsigned int*)g,
                                   (__attribute__((address_space(3))) unsigned int*)l, 16, 0, 0);
}

// ---------------------------------------------------------------------------
// fp32 -> bf16 (round-to-nearest-even), vectorized. n4 = n/4.
// ---------------------------------------------------------------------------
__global__ __launch_bounds__(256) void convert_to_bf16(const float* __restrict__ src,
                                                       unsigned short* __restrict__ dst,
                                                       int n4) {
  int i = blockIdx.x * blockDim.x + threadIdx.x;
  int stride = gridDim.x * blockDim.x;
  for (; i < n4; i += stride) {
    f32x4 v = *(const f32x4*)(src + 4 * (size_t)i);
    u16x4 o;
    o.x = f2bf(v.x); o.y = f2bf(v.y); o.z = f2bf(v.z); o.w = f2bf(v.w);
    *(u16x4*)(dst + 4 * (size_t)i) = o;
  }
}

// ---------------------------------------------------------------------------
// C[M,N] = A[M,K] * B[N,K]^T, bf16 in, fp32 accum, bf16 OR fp32 out (OUT_F32).
// 128x128 tile, BK=32, 4 waves (2x2 of 64x64), mfma_f32_16x16x32_bf16.
// m97-style: global_load_lds width=16 staging into UNPADDED 128x32 LDS
// (layout must be contiguous in lane order: row = lane/4, col = (lane%4)*8).
// ---------------------------------------------------------------------------
template <bool OUT_F32>
__global__ __launch_bounds__(256) void gemm_bt_bf16(
    const unsigned short* __restrict__ A, const unsigned short* __restrict__ B,
    void* __restrict__ Cv, int lda, int ldb, int ldc, int K) {
  __shared__ alignas(16) unsigned short As[128 * 32];
  __shared__ alignas(16) unsigned short Bs[128 * 32];

  const int t    = threadIdx.x;
  const int lane = t & 63;
  const int w    = t >> 6;
  const int wm   = (w >> 1) * 64;
  const int wn   = (w & 1) * 64;
  const size_t m0 = (size_t)blockIdx.y * 128;
  const size_t n0 = (size_t)blockIdx.x * 128;

  f32x4 acc[4][4] = {};

  // wave w stages rows [w*32, w*32+32) of each tile: 2 lds-dma per matrix
  const int srow = w * 32 + (lane >> 2);
  const int scol = (lane & 3) * 8;
  const unsigned short* gA0 = &A[(m0 + srow) * (size_t)lda + scol];
  const unsigned short* gA1 = gA0 + 16 * (size_t)lda;
  const unsigned short* gB0 = &B[(n0 + srow) * (size_t)ldb + scol];
  const unsigned short* gB1 = gB0 + 16 * (size_t)ldb;
  unsigned short* lA0 = &As[(w * 32) * 32];
  unsigned short* lA1 = &As[(w * 32 + 16) * 32];
  unsigned short* lB0 = &Bs[(w * 32) * 32];
  unsigned short* lB1 = &Bs[(w * 32 + 16) * 32];

  const int fr = lane & 15;
  const int kb = (lane >> 4) * 8;

  for (int k0 = 0; k0 < K; k0 += 32) {
    load_lds16(gA0 + k0, lA0);
    load_lds16(gA1 + k0, lA1);
    load_lds16(gB0 + k0, lB0);
    load_lds16(gB1 + k0, lB1);
    __syncthreads();
    short8 af[4], bf[4];
#pragma unroll
    for (int mt = 0; mt < 4; mt++) af[mt] = *(const short8*)&As[(wm + mt * 16 + fr) * 32 + kb];
#pragma unroll
    for (int nt = 0; nt < 4; nt++) bf[nt] = *(const short8*)&Bs[(wn + nt * 16 + fr) * 32 + kb];
#pragma unroll
    for (int mt = 0; mt < 4; mt++)
#pragma unroll
      for (int nt = 0; nt < 4; nt++)
        acc[mt][nt] = __builtin_amdgcn_mfma_f32_16x16x32_bf16(af[mt], bf[nt], acc[mt][nt], 0, 0, 0);
    __syncthreads();
  }

  const int r4 = (lane >> 4) * 4;
  const int cc = lane & 15;
#pragma unroll
  for (int mt = 0; mt < 4; mt++)
#pragma unroll
    for (int nt = 0; nt < 4; nt++) {
      size_t row = m0 + wm + mt * 16 + r4;
      size_t col = n0 + wn + nt * 16 + cc;
#pragma unroll
      for (int r = 0; r < 4; r++) {
        if (OUT_F32) ((float*)Cv)[(row + r) * ldc + col] = acc[mt][nt][r];
        else ((unsigned short*)Cv)[(row + r) * ldc + col] = f2bf(acc[mt][nt][r]);
      }
    }
}

// ---------------------------------------------------------------------------
// RMSNorm + RoPE, IN PLACE on qkv. One wave per (token, q-or-k head).
// ---------------------------------------------------------------------------
__global__ __launch_bounds__(64) void normrope(
    unsigned short* __restrict__ qkv, const int* __restrict__ pos,
    const unsigned short* __restrict__ qw, const unsigned short* __restrict__ kw) {
  const int h    = blockIdx.x;                       // 0..35 (32 q + 4 k)
  const int tok  = blockIdx.z * SEQ + blockIdx.y;
  const int lane = threadIdx.x;

  const unsigned short* w = (h < NH) ? qw : kw;
  const size_t src = (size_t)tok * QKV_O + (size_t)h * HD;

  float x1 = bf2f(qkv[src + lane]);
  float x2 = bf2f(qkv[src + lane + 64]);
  float ss = x1 * x1 + x2 * x2;
#pragma unroll
  for (int off = 32; off; off >>= 1) ss += __shfl_xor(ss, off);
  float r = rsqrtf(ss * (1.0f / 128.0f) + 1e-6f);
  float n1 = x1 * r * bf2f(w[lane]);
  float n2 = x2 * r * bf2f(w[lane + 64]);

  float p = (float)pos[tok];
  float inv_freq = expf((float)lane * (-13.815510557964274f / 64.0f));  // 1e6^(-lane/64)
  float ang = p * inv_freq;
  float c = cosf(ang), s = sinf(ang);
  qkv[src + lane]      = f2bf(n1 * c - n2 * s);
  qkv[src + lane + 64] = f2bf(n2 * c + n1 * s);
}

// ---------------------------------------------------------------------------
// V transpose: vt[b][kvh][d][s] <- qkv v-slot. One block per (kv-tile 64, kvh, b).
// Coalesced uint4 read into LDS, coalesced u16x8 write out.
// ---------------------------------------------------------------------------
__global__ __launch_bounds__(256) void transpose_v(const unsigned short* __restrict__ qkv,
                                                   unsigned short* __restrict__ vt) {
  __shared__ alignas(16) unsigned short Vs[64][136];
  const int k0 = blockIdx.x * 64, kvh = blockIdx.y, b = blockIdx.z;
  const int t = threadIdx.x;
  const int voff = (NH + NKV) * HD + kvh * HD;
  {
    const int row = t >> 2, cb = (t & 3) * 8;
    const size_t gb = (size_t)(b * SEQ + k0 + row) * QKV_O + voff;
#pragma unroll
    for (int r = 0; r < 4; r++)
      *(uint4*)&Vs[row][cb + 32 * r] = *(const uint4*)&qkv[gb + cb + 32 * r];
  }
  __syncthreads();
  const int d = t >> 1, half = t & 1;
  const size_t ob = ((size_t)((b * NKV + kvh) * HD + d)) * SEQ + k0 + half * 32;
#pragma unroll
  for (int i = 0; i < 4; i++) {
    u16x8 vv;
#pragma unroll
    for (int j = 0; j < 8; j++) vv[j] = Vs[half * 32 + i * 8 + j][d];
    *(u16x8*)&vt[ob + i * 8] = vv;
  }
}

// ---------------------------------------------------------------------------
// MFMA causal GQA flash attention (v2).
// Block: 256 thr (4 waves), q-tile 64 (wave w: rows q0+16w..+15), KV tiles 64.
// ScT[kv][q] = K @ Q^T (C-layout: row=kv=(lane>>4)*4+reg, col=q=lane&15);
// per-q softmax in-lane over 16 regs + shfl_xor(16,32); P -> LDS (A-frag);
// PV with Vt tile staged from pre-transposed global vt (coalesced uint4).
// Q frags read directly from global (no Qs tile). LDS ~45 KB -> 3 blocks/CU.
// ---------------------------------------------------------------------------
__global__ __launch_bounds__(256) void flash_mfma(unsigned short* __restrict__ qkv,
                                                  const unsigned short* __restrict__ vt) {
  __shared__ alignas(16) unsigned short Ks[64][136];
  __shared__ alignas(16) unsigned short Vt[128][72];
  __shared__ alignas(16) unsigned short Ps[4][16][72];
  __shared__ alignas(16) float bcast[4][16];

  const int qt = (int)gridDim.x - 1 - (int)blockIdx.x; // heavy blocks first
  const int h = blockIdx.y, b = blockIdx.z;
  const int t = threadIdx.x;
  const int lane = t & 63, w = t >> 6;
  const int c = lane & 15, g = lane >> 4;
  const int q0 = qt * 64;
  const int kvh = h >> 3;                              // GQA 32->4
  const int koff = NH * HD + kvh * HD;
  const float scale = 0.08838834764831845f;            // 128^-0.5

  // Q B-frags straight from global (one-time, 4 x 16B per lane)
  short8 qf[4];
  {
    const size_t qrow = (size_t)(b * SEQ + q0 + w * 16 + c) * QKV_O + h * HD;
#pragma unroll
    for (int ks = 0; ks < 4; ks++)
      qf[ks] = *(const short8*)&qkv[qrow + ks * 32 + g * 8];
  }

  f32x4 O[8] = {};                // 8 d-tiles x 4 row-regs
  float m_i = -1e30f, l_i = 0.0f; // per-q state (q = col c)

  const int nkt = qt + 1;
  for (int kt = 0; kt < nkt; kt++) {
    const int k0 = kt * 64;
    __syncthreads();
    // stage K rows (coalesced uint4)
    {
      const int row = t >> 2, cb = (t & 3) * 8;
      const size_t gb = (size_t)(b * SEQ + k0 + row) * QKV_O + koff;
#pragma unroll
      for (int r = 0; r < 4; r++)
        *(uint4*)&Ks[row][cb + 32 * r] = *(const uint4*)&qkv[gb + cb + 32 * r];
    }
    // stage Vt tile from pre-transposed global (coalesced uint4)
    {
      const int d = t >> 1, half = t & 1;
      const size_t gb = ((size_t)((b * NKV + kvh) * HD + d)) * SEQ + k0 + half * 32;
#pragma unroll
      for (int i = 0; i < 4; i++)
        *(uint4*)&Vt[d][half * 32 + i * 8] = *(const uint4*)&vt[gb + i * 8];
    }
    __syncthreads();

    // ScT[kv 64][q 16] per wave: 4 mt x 4 ks MFMAs
    f32x4 sc[4];
#pragma unroll
    for (int mt = 0; mt < 4; mt++) sc[mt] = (f32x4){0.f, 0.f, 0.f, 0.f};
#pragma unroll
    for (int ks = 0; ks < 4; ks++) {
#pragma unroll
      for (int mt = 0; mt < 4; mt++) {
        short8 kf = *(const short8*)&Ks[mt * 16 + c][ks * 32 + g * 8];
        sc[mt] = __builtin_amdgcn_mfma_f32_16x16x32_bf16(kf, qf[ks], sc[mt], 0, 0, 0);
      }
    }

    // scale + causal mask (wave-uniform branch)
    const int qrow = q0 + w * 16 + c;
    const bool need_mask = (k0 + 63 > q0 + w * 16);
    float scv[16];
#pragma unroll
    for (int mt = 0; mt < 4; mt++)
#pragma unroll
      for (int r = 0; r < 4; r++) {
        float s = sc[mt][r] * scale;
        if (need_mask && (k0 + mt * 16 + g * 4 + r > qrow)) s = -1e30f;
        scv[mt * 4 + r] = s;
      }

    // per-q (column) online softmax
    float mx = scv[0];
#pragma unroll
    for (int i = 1; i < 16; i++) mx = fmaxf(mx, scv[i]);
    mx = fmaxf(mx, __shfl_xor(mx, 16));
    mx = fmaxf(mx, __shfl_xor(mx, 32));
    float m_new = fmaxf(m_i, mx);
    float alpha = __expf(m_i - m_new);
    float psum = 0.0f;
    unsigned short pb[16];
#pragma unroll
    for (int i = 0; i < 16; i++) {
      float p = __expf(scv[i] - m_new);
      psum += p;
      pb[i] = f2bf(p);
    }
    psum += __shfl_xor(psum, 16);
    psum += __shfl_xor(psum, 32);
    l_i = l_i * alpha + psum;
    m_i = m_new;

    // write P[q][kv] bf16 into per-wave region
#pragma unroll
    for (int mt = 0; mt < 4; mt++) {
      u16x4 p4 = {pb[mt * 4 + 0], pb[mt * 4 + 1], pb[mt * 4 + 2], pb[mt * 4 + 3]};
      *(u16x4*)&Ps[w][c][mt * 16 + g * 4] = p4;
    }
    // broadcast alpha from col-space (q=c) to row-space (q=g*4+r)
    if (g == 0) bcast[w][c] = alpha;
    f32x4 a4 = *(const f32x4*)&bcast[w][g * 4];
#pragma unroll
    for (int nt = 0; nt < 8; nt++)
#pragma unroll
      for (int r = 0; r < 4; r++) O[nt][r] *= a4[r];

    // PV: O[q][d] += P(16x64) @ Vt-frags; 2 ks x 8 nt MFMAs
#pragma unroll
    for (int ks = 0; ks < 2; ks++) {
      short8 pf = *(const short8*)&Ps[w][c][ks * 32 + g * 8];
#pragma unroll
      for (int nt = 0; nt < 8; nt++) {
        short8 vf = *(const short8*)&Vt[nt * 16 + c][ks * 32 + g * 8];
        O[nt] = __builtin_amdgcn_mfma_f32_16x16x32_bf16(pf, vf, O[nt], 0, 0, 0);
      }
    }
  }

  // epilogue: O /= l (l bcast col->row), write bf16 in place (q region)
  if (g == 0) bcast[w][c] = l_i;
  __syncthreads();
  f32x4 l4 = *(const f32x4*)&bcast[w][g * 4];
  f32x4 li;
#pragma unroll
  for (int r = 0; r < 4; r++) li[r] = 1.0f / l4[r];
#pragma unroll
  for (int nt = 0; nt < 8; nt++)
#pragma unroll
    for (int r = 0; r < 4; r++) {
      size_t addr = (size_t)(b * SEQ + q0 + w * 16 + g * 4 + r) * QKV_O + h * HD + nt * 16 + c;
      qkv[addr] = f2bf(O[nt][r] * li[r]);
    }
}

// ---------------------------------------------------------------------------
extern "C" void kernel_launch(void* const* d_in, const int* in_sizes, int n_in,
                              void* d_out, int out_size, void* d_ws, size_t ws_size,
                              hipStream_t stream) {
  const float* hidden_f = (const float*)d_in[0];
  const int* positions  = (const int*)d_in[1];
  const float* wqkv_f   = (const float*)d_in[2];
  const float* wo_f     = (const float*)d_in[3];
  const float* qn_f     = (const float*)d_in[4];
  const float* kn_f     = (const float*)d_in[5];
  float* out            = (float*)d_out;  // reference output dtype is float32

  char* ws = (char*)d_ws;
  unsigned short* hidden_c = (unsigned short*)ws;                    // 16,777,216
  unsigned short* wqkv_c   = (unsigned short*)(ws + 16777216);       // 20,971,520
  unsigned short* wo_c     = (unsigned short*)(ws + 37748736);       // 16,777,216
  unsigned short* qn_c     = (unsigned short*)(ws + 54525952);       // 256
  unsigned short* kn_c     = (unsigned short*)(ws + 54526208);       // 256
  unsigned short* qkv      = (unsigned short*)(ws + 54526464);       // 41,943,040
  unsigned short* vt_g     = (unsigned short*)(ws + 96469504);       // 4,194,304  (total ~96 MiB)

  convert_to_bf16<<<1024, 256, 0, stream>>>(hidden_f, hidden_c, NTOK * HID / 4);
  convert_to_bf16<<<1024, 256, 0, stream>>>(wqkv_f, wqkv_c, QKV_O * HID / 4);
  convert_to_bf16<<<1024, 256, 0, stream>>>(wo_f, wo_c, HID * NH * HD / 4);
  convert_to_bf16<<<1, 32, 0, stream>>>(qn_f, qn_c, HD / 4);
  convert_to_bf16<<<1, 32, 0, stream>>>(kn_f, kn_c, HD / 4);

  // K1: qkv = hidden @ w_qkv^T   (4096 x 5120 x 2048), bf16 out
  gemm_bt_bf16<false><<<dim3(QKV_O / 128, NTOK / 128), 256, 0, stream>>>(
      hidden_c, wqkv_c, qkv, HID, HID, QKV_O, HID);
  // K2: rmsnorm + rope, in place on q & k head slots
  normrope<<<dim3(NH + NKV, SEQ, BATCH), 64, 0, stream>>>(qkv, positions, qn_c, kn_c);
  // K2b: V transpose into vt_g
  transpose_v<<<dim3(SEQ / 64, NKV, BATCH), 256, 0, stream>>>(qkv, vt_g);
  // K3: MFMA causal GQA attention, attn in place into q region of qkv
  flash_mfma<<<dim3(SEQ / 64, NH, BATCH), 256, 0, stream>>>(qkv, vt_g);
  // K4: out = attn @ w_o^T   (4096 x 2048 x 4096), fp32 out
  gemm_bt_bf16<true><<<dim3(HID / 128, NTOK / 128), 256, 0, stream>>>(
      qkv, wo_c, out, QKV_O, NH * HD, HID, NH * HD);
}